// Round 7
// baseline (335.002 us; speedup 1.0000x reference)
//
#include <hip/hip_runtime.h>
#include <math.h>

typedef unsigned short u16;
typedef __attribute__((ext_vector_type(8))) short short8;
typedef __attribute__((ext_vector_type(4))) float f32x4;

#define MFMA16x16x32(a, b, c) __builtin_amdgcn_mfma_f32_16x16x32_bf16((a), (b), (c), 0, 0, 0)
#define GLL16(g, s)                                                        \
  __builtin_amdgcn_global_load_lds(                                        \
      (const __attribute__((address_space(1))) void*)(g),                  \
      (__attribute__((address_space(3))) void*)(s), 16, 0, 0)

__device__ __forceinline__ u16 f32_to_bf16(float x) {
  union { float f; unsigned u; } v; v.f = x;
  unsigned r = v.u + 0x7FFFu + ((v.u >> 16) & 1u);
  return (u16)(r >> 16);
}

// ---------------- fp32 -> bf16 convert ----------------
__global__ void cvt_f32_bf16(const float* __restrict__ in, u16* __restrict__ out, int n4) {
  int i = blockIdx.x * blockDim.x + threadIdx.x;
  int stride = gridDim.x * blockDim.x;
  for (; i < n4; i += stride) {
    float4 v = ((const float4*)in)[i];
    ushort4 o;
    o.x = f32_to_bf16(v.x);
    o.y = f32_to_bf16(v.y);
    o.z = f32_to_bf16(v.z);
    o.w = f32_to_bf16(v.w);
    ((ushort4*)out)[i] = o;
  }
}

// ======== m201-style 256x256 8-phase bf16 NT GEMM ========
// BM=BN=256, BK=64, 8 waves (2M x 4N), per-wave 128x64.
// LDS 128KB: As/Bs [buf][half][128x64] XOR-swizzled via pre-inverse-swizzled src.
// 4 phases per K-tile, 16 MFMA (one C-quadrant) each, 2 barriers/phase.
// Stage: ph0->Ah0(t+1), ph1->Ah1(t+1), ph2->Bh0(t+2), ph3->Bh1(t+2).
// One vmcnt(6) per K-tile (at ph0); vmcnt(0) only at last tile.
template <int OUT_BF16>
__global__ __launch_bounds__(512, 2) void gemm_nt_256(
    const u16* __restrict__ A,      // M x K row-major bf16
    const u16* __restrict__ B,      // N x K row-major bf16
    const float* __restrict__ bias, // length N
    void* __restrict__ C,           // M x N (bf16 or f32)
    int M, int N, int K)
{
  __shared__ u16 As[2][2][8192];   // [buf][half][128 rows x 64 cols]
  __shared__ u16 Bs[2][2][8192];

  const int tid = threadIdx.x;
  const int w = tid >> 6, l = tid & 63;
  const int l15 = l & 15, l4 = l >> 4;
  const int wm = w >> 2, wn = w & 3;
  const long bm = (long)blockIdx.y * 256, bn = (long)blockIdx.x * 256;
  const int NT = K >> 6;

  // staging source (inverse-swizzled): LDS byte q of a half holds global
  // (row q>>7, colbyte (q&127)^((row&7)<<4)); thread covers q = tid*16 (+j*8192)
  const int r0 = tid >> 3;
  const int cb0 = ((tid * 16) & 127) ^ ((r0 & 7) << 4);
  const u16* aS = A + (bm + r0) * (long)K + (cb0 >> 1);
  const u16* bS = B + (bn + r0) * (long)K + (cb0 >> 1);
  const long rK64 = 64 * (long)K, rK128 = 128 * (long)K;
  const int ldst = w * 512;  // u16 units within a half (wave-uniform)

#define STG_A(buf, half, tt)                                                   \
  do {                                                                         \
    GLL16(aS + (half) * rK128 + (long)(tt) * 64, &As[buf][half][ldst]);        \
    GLL16(aS + (half) * rK128 + rK64 + (long)(tt) * 64,                        \
          &As[buf][half][ldst + 4096]);                                        \
  } while (0)
#define STG_B(buf, half, tt)                                                   \
  do {                                                                         \
    GLL16(bS + (half) * rK128 + (long)(tt) * 64, &Bs[buf][half][ldst]);        \
    GLL16(bS + (half) * rK128 + rK64 + (long)(tt) * 64,                        \
          &Bs[buf][half][ldst + 4096]);                                        \
  } while (0)

  const f32x4 z4 = {0.f, 0.f, 0.f, 0.f};
  f32x4 acc[8][4];
  #pragma unroll
  for (int m = 0; m < 8; ++m)
    #pragma unroll
    for (int n = 0; n < 4; ++n) acc[m][n] = z4;

  const int swz = (l15 & 7) << 4;
  const int xo0 = (l4 * 16) ^ swz;
  const int xo1 = (64 + l4 * 16) ^ swz;

  short8 af[4][2], bf[4][2];

  // prologue: A(0) both halves, B(0) both halves, B(1) both halves (12 GLL)
  STG_A(0, 0, 0); STG_A(0, 1, 0);
  STG_B(0, 0, 0); STG_B(0, 1, 0);
  STG_B(1, 0, 1); STG_B(1, 1, 1);

  for (int t = 0; t < NT; ++t) {
    const int bufo = t & 1, nb = bufo ^ 1;
    const char* aH = (const char*)&As[bufo][wm][0] + l15 * 128;
    const char* bH = (const char*)&Bs[bufo][wn >> 1][0] + ((wn & 1) * 64 + l15) * 128;

    // ---- phase 0: stage Ah0(t+1); wait; quadrant (m0-3 x n0-1) ----
    if (t + 1 < NT) STG_A(nb, 0, t + 1);
    if (t == NT - 1) asm volatile("s_waitcnt vmcnt(0)" ::: "memory");
    else             asm volatile("s_waitcnt vmcnt(6)" ::: "memory");
    __builtin_amdgcn_s_barrier();
    #pragma unroll
    for (int m = 0; m < 4; ++m) {
      af[m][0] = *(const short8*)(aH + m * 2048 + xo0);
      af[m][1] = *(const short8*)(aH + m * 2048 + xo1);
    }
    #pragma unroll
    for (int n = 0; n < 2; ++n) {
      bf[n][0] = *(const short8*)(bH + n * 2048 + xo0);
      bf[n][1] = *(const short8*)(bH + n * 2048 + xo1);
    }
    __builtin_amdgcn_s_setprio(1);
    #pragma unroll
    for (int m = 0; m < 4; ++m)
      #pragma unroll
      for (int n = 0; n < 2; ++n) {
        acc[m][n] = MFMA16x16x32(af[m][0], bf[n][0], acc[m][n]);
        acc[m][n] = MFMA16x16x32(af[m][1], bf[n][1], acc[m][n]);
      }
    __builtin_amdgcn_s_setprio(0);
    __builtin_amdgcn_s_barrier();

    // ---- phase 1: stage Ah1(t+1); quadrant (m0-3 x n2-3) ----
    if (t + 1 < NT) STG_A(nb, 1, t + 1);
    __builtin_amdgcn_s_barrier();
    #pragma unroll
    for (int n = 0; n < 2; ++n) {
      bf[2 + n][0] = *(const short8*)(bH + (2 + n) * 2048 + xo0);
      bf[2 + n][1] = *(const short8*)(bH + (2 + n) * 2048 + xo1);
    }
    __builtin_amdgcn_s_setprio(1);
    #pragma unroll
    for (int m = 0; m < 4; ++m)
      #pragma unroll
      for (int n = 2; n < 4; ++n) {
        acc[m][n] = MFMA16x16x32(af[m][0], bf[n][0], acc[m][n]);
        acc[m][n] = MFMA16x16x32(af[m][1], bf[n][1], acc[m][n]);
      }
    __builtin_amdgcn_s_setprio(0);
    __builtin_amdgcn_s_barrier();

    // ---- phase 2: stage Bh0(t+2); quadrant (m4-7 x n0-1) ----
    if (t + 2 < NT) STG_B(bufo, 0, t + 2);
    __builtin_amdgcn_s_barrier();
    #pragma unroll
    for (int m = 0; m < 4; ++m) {
      af[m][0] = *(const short8*)(aH + (4 + m) * 2048 + xo0);
      af[m][1] = *(const short8*)(aH + (4 + m) * 2048 + xo1);
    }
    __builtin_amdgcn_s_setprio(1);
    #pragma unroll
    for (int m = 0; m < 4; ++m)
      #pragma unroll
      for (int n = 0; n < 2; ++n) {
        acc[4 + m][n] = MFMA16x16x32(af[m][0], bf[n][0], acc[4 + m][n]);
        acc[4 + m][n] = MFMA16x16x32(af[m][1], bf[n][1], acc[4 + m][n]);
      }
    __builtin_amdgcn_s_setprio(0);
    __builtin_amdgcn_s_barrier();

    // ---- phase 3: stage Bh1(t+2); quadrant (m4-7 x n2-3) ----
    if (t + 2 < NT) STG_B(bufo, 1, t + 2);
    __builtin_amdgcn_s_barrier();
    __builtin_amdgcn_s_setprio(1);
    #pragma unroll
    for (int m = 0; m < 4; ++m)
      #pragma unroll
      for (int n = 2; n < 4; ++n) {
        acc[4 + m][n] = MFMA16x16x32(af[m][0], bf[n][0], acc[4 + m][n]);
        acc[4 + m][n] = MFMA16x16x32(af[m][1], bf[n][1], acc[4 + m][n]);
      }
    __builtin_amdgcn_s_setprio(0);
    __builtin_amdgcn_s_barrier();
  }
#undef STG_A
#undef STG_B

  // ---- epilogue ----
  #pragma unroll
  for (int m = 0; m < 8; ++m) {
    const long row0 = bm + wm * 128 + m * 16 + l4 * 4;
    #pragma unroll
    for (int n = 0; n < 4; ++n) {
      const long col = bn + wn * 64 + n * 16 + l15;
      const float bv = bias[col];
      #pragma unroll
      for (int r = 0; r < 4; ++r) {
        const float v = acc[m][n][r] + bv;
        if (OUT_BF16)
          ((u16*)C)[(row0 + r) * (long)N + col] = f32_to_bf16(v);
        else
          ((float*)C)[(row0 + r) * (long)N + col] = v;
      }
    }
  }
}

// ---------------- 128x256 8-phase GEMM (kept for out-proj: 256 balanced blocks) ----------------
template <int OUT_BF16>
__global__ __launch_bounds__(512, 2) void gemm_nt_8p(
    const u16* __restrict__ A, const u16* __restrict__ B,
    const float* __restrict__ bias, void* __restrict__ C,
    int M, int N, int K)
{
  __shared__ u16 As[2][8192];
  __shared__ u16 Bs[2][16384];
  const int tid = threadIdx.x;
  const int w = tid >> 6, l = tid & 63;
  const int l15 = l & 15, l4 = l >> 4;
  const int wm = w >> 2, wn = w & 3;
  const long bm = (long)blockIdx.y * 128, bn = (long)blockIdx.x * 256;
  const int NT = K >> 6;

  const u16 *aSrc0, *aSrc1, *bSrc0, *bSrc1;
  {
    int q = w * 2048 + l * 16;
    int r = q >> 7, cb = (q & 127) ^ ((r & 7) << 4);
    aSrc0 = A + (bm + r) * (long)K + (cb >> 1);
    bSrc0 = B + (bn + r) * (long)K + (cb >> 1);
    q += 1024;
    r = q >> 7; cb = (q & 127) ^ ((r & 7) << 4);
    aSrc1 = A + (bm + r) * (long)K + (cb >> 1);
    bSrc1 = B + (bn + r) * (long)K + (cb >> 1);
  }
  const long bHS = 128 * (long)K;
  const int ldsA = w * 1024;

  const f32x4 z4 = {0.f, 0.f, 0.f, 0.f};
  f32x4 acc[4][4];
  #pragma unroll
  for (int m = 0; m < 4; ++m)
    #pragma unroll
    for (int n = 0; n < 4; ++n) acc[m][n] = z4;

  const int xo0 = (l4 * 16) ^ ((l15 & 7) << 4);
  const int xo1 = (64 + l4 * 16) ^ ((l15 & 7) << 4);
  const char* aRd = (const char*)&As[0][0] + (wm * 64 + l15) * 128;
  const char* bRd = (const char*)&Bs[0][0] + (wn * 32 + l15) * 128;

  GLL16(aSrc0, &As[0][ldsA]);
  GLL16(aSrc1, &As[0][ldsA + 512]);
  GLL16(bSrc0, &Bs[0][ldsA]);
  GLL16(bSrc1, &Bs[0][ldsA + 512]);
  GLL16(bSrc0 + bHS, &Bs[0][8192 + ldsA]);
  GLL16(bSrc1 + bHS, &Bs[0][8192 + ldsA + 512]);

  short8 af[4][2], bf[4][2];

  for (int t = 0; t < NT; ++t) {
    const int nxt = t + 1;
    const int bufo = t & 1;

    if (nxt < NT) {
      const long ko = (long)nxt * 64;
      const int nb = nxt & 1;
      GLL16(aSrc0 + ko, &As[nb][ldsA]);
      GLL16(aSrc1 + ko, &As[nb][ldsA + 512]);
      GLL16(bSrc0 + ko, &Bs[nb][ldsA]);
      GLL16(bSrc1 + ko, &Bs[nb][ldsA + 512]);
      asm volatile("s_waitcnt vmcnt(6)\ns_barrier" ::: "memory");
    } else {
      asm volatile("s_waitcnt vmcnt(2)\ns_barrier" ::: "memory");
    }
    const char* ab = aRd + bufo * 16384;
    const char* bb = bRd + bufo * 32768;
    #pragma unroll
    for (int m = 0; m < 4; ++m) {
      af[m][0] = *(const short8*)(ab + m * 2048 + xo0);
      af[m][1] = *(const short8*)(ab + m * 2048 + xo1);
    }
    #pragma unroll
    for (int n = 0; n < 2; ++n) {
      bf[n][0] = *(const short8*)(bb + n * 2048 + xo0);
      bf[n][1] = *(const short8*)(bb + n * 2048 + xo1);
    }
    __builtin_amdgcn_s_setprio(1);
    #pragma unroll
    for (int m = 0; m < 4; ++m)
      #pragma unroll
      for (int n = 0; n < 2; ++n) {
        acc[m][n] = MFMA16x16x32(af[m][0], bf[n][0], acc[m][n]);
        acc[m][n] = MFMA16x16x32(af[m][1], bf[n][1], acc[m][n]);
      }
    __builtin_amdgcn_s_setprio(0);

    if (nxt < NT) {
      const long ko = (long)nxt * 64;
      const int nb = nxt & 1;
      GLL16(bSrc0 + bHS + ko, &Bs[nb][8192 + ldsA]);
      GLL16(bSrc1 + bHS + ko, &Bs[nb][8192 + ldsA + 512]);
      asm volatile("s_waitcnt vmcnt(6)\ns_barrier" ::: "memory");
    } else {
      asm volatile("s_waitcnt vmcnt(0)\ns_barrier" ::: "memory");
    }
    const char* bb1 = bb + 16384;
    #pragma unroll
    for (int n = 0; n < 2; ++n) {
      bf[2 + n][0] = *(const short8*)(bb1 + n * 2048 + xo0);
      bf[2 + n][1] = *(const short8*)(bb1 + n * 2048 + xo1);
    }
    __builtin_amdgcn_s_setprio(1);
    #pragma unroll
    for (int m = 0; m < 4; ++m)
      #pragma unroll
      for (int n = 2; n < 4; ++n) {
        acc[m][n] = MFMA16x16x32(af[m][0], bf[n][0], acc[m][n]);
        acc[m][n] = MFMA16x16x32(af[m][1], bf[n][1], acc[m][n]);
      }
    __builtin_amdgcn_s_setprio(0);
  }

  #pragma unroll
  for (int m = 0; m < 4; ++m) {
    const long row0 = bm + wm * 64 + m * 16 + l4 * 4;
    #pragma unroll
    for (int n = 0; n < 4; ++n) {
      const long col = bn + wn * 32 + (n & 1) * 16 + (n >> 1) * 128 + l15;
      const float bv = bias[col];
      #pragma unroll
      for (int r = 0; r < 4; ++r) {
        const float v = acc[m][n][r] + bv;
        if (OUT_BF16)
          ((u16*)C)[(row0 + r) * (long)N + col] = f32_to_bf16(v);
        else
          ((float*)C)[(row0 + r) * (long)N + col] = v;
      }
    }
  }
}

// ---------------- repack K and V into per-tile LDS images ----------------
__global__ __launch_bounds__(256) void repack_kv(
    const u16* __restrict__ qkv, u16* __restrict__ kimg, u16* __restrict__ vimg)
{
  const int t = blockIdx.x;
  const int h = blockIdx.y, b = blockIdx.z;
  const int tid = threadIdx.x;
  __shared__ u16 Vl[64][136];

  const long qbase = ((long)(b * 2048 + t * 64)) * 6144 + h * 128;
  u16* kout = kimg + (((long)(b * 16 + h) * 32 + t) * 8192);
  u16* vout = vimg + (((long)(b * 16 + h) * 32 + t) * 8192);

  #pragma unroll
  for (int i = 0; i < 4; ++i) {
    const int j = tid + i * 256;
    {
      const int r = j >> 4, c8 = (j & 15) * 8;
      uint4 v = *(const uint4*)(qkv + qbase + (long)r * 6144 + 4096 + c8);
      *(uint4*)(&Vl[r][c8]) = v;
    }
    {
      const int byte = j * 16;
      const int r = byte >> 8;
      const int wv = (byte & 255) ^ ((r & 7) << 4);
      const int d0 = wv >> 1;
      uint4 v = *(const uint4*)(qkv + qbase + (long)r * 6144 + 2048 + d0);
      *(uint4*)(kout + j * 8) = v;
    }
  }
  __syncthreads();
  #pragma unroll
  for (int i = 0; i < 4; ++i) {
    const int j = tid + i * 256;
    const int byte = j * 16;
    const int d = byte >> 7;
    const int wv = (byte & 127) ^ ((d & 7) << 4);
    const int k0 = wv >> 1;
    u16 tmp[8];
    #pragma unroll
    for (int m = 0; m < 8; ++m) tmp[m] = Vl[k0 + m][d];
    *(uint4*)(vout + j * 8) = *(const uint4*)tmp;
  }
}

// ---------------- flash causal attention with alibi ----------------
__global__ __launch_bounds__(256) void attn_kernel(
    const u16* __restrict__ qkv,
    const u16* __restrict__ kimg,
    const u16* __restrict__ vimg,
    u16* __restrict__ ctx)
{
  const int S = 2048, NHD = 6144, NT = 32;
  const int p = blockIdx.x, h = blockIdx.y, b = blockIdx.z;
  const int tid = threadIdx.x;
  const int w = tid >> 6, l = tid & 63;
  const int l15 = l & 15, l4 = l >> 4;

  __shared__ u16 Ks[64 * 128];
  __shared__ u16 Vt[128 * 64];
  __shared__ u16 Ps[4][16 * 64];

  const float LOG2E = 1.44269504088896f;
  const float c1 = 0.08838834764831845f * LOG2E;
  const float slope2 = exp2f(-0.5f * (float)(h + 1)) * LOG2E;

  const f32x4 z4 = {0.f, 0.f, 0.f, 0.f};

  for (int pass = 0; pass < 2; ++pass) {
    const int qblk = pass ? (NT - 1 - p) : p;
    const int qb0 = qblk * 64;

    short8 qf[4];
    {
      const int qrow = qb0 + w * 16 + l15;
      const u16* qp = qkv + (long)(b * S + qrow) * NHD + h * 128 + l4 * 8;
      #pragma unroll
      for (int kc = 0; kc < 4; ++kc) qf[kc] = *(const short8*)(qp + kc * 32);
    }

    f32x4 o[8];
    #pragma unroll
    for (int i = 0; i < 8; ++i) o[i] = z4;
    float m_r[4] = {-3.0e38f, -3.0e38f, -3.0e38f, -3.0e38f};
    float l_r[4] = {0.f, 0.f, 0.f, 0.f};

    for (int kt = 0; kt <= qblk; ++kt) {
      const u16* ksrc = kimg + (((long)(b * 16 + h) * NT + kt) * 8192);
      const u16* vsrc = vimg + (((long)(b * 16 + h) * NT + kt) * 8192);
      #pragma unroll
      for (int i = 0; i < 4; ++i) {
        const int chunk = w * 4 + i;
        __builtin_amdgcn_global_load_lds(
            (const __attribute__((address_space(1))) void*)(ksrc + chunk * 512 + l * 8),
            (__attribute__((address_space(3))) void*)(Ks + chunk * 512), 16, 0, 0);
        __builtin_amdgcn_global_load_lds(
            (const __attribute__((address_space(1))) void*)(vsrc + chunk * 512 + l * 8),
            (__attribute__((address_space(3))) void*)(Vt + chunk * 512), 16, 0, 0);
      }
      __syncthreads();

      f32x4 sf[4];
      #pragma unroll
      for (int nt = 0; nt < 4; ++nt) sf[nt] = z4;
      #pragma unroll
      for (int nt = 0; nt < 4; ++nt) {
        const int krow = nt * 16 + l15;
        #pragma unroll
        for (int kc = 0; kc < 4; ++kc) {
          int kbyte = (krow * 256 + kc * 64 + l4 * 16) ^ ((krow & 7) << 4);
          const short8 kf = *(const short8*)((const char*)Ks + kbyte);
          sf[nt] = MFMA16x16x32(qf[kc], kf, sf[nt]);
        }
      }

      float add_nt[4];
      int kg_nt[4];
      #pragma unroll
      for (int nt = 0; nt < 4; ++nt) {
        kg_nt[nt] = kt * 64 + nt * 16 + l15;
        add_nt[nt] = slope2 * (float)(kg_nt[nt] - (S - 1));
      }
      const bool diag = (kt == qblk);
      float alpha[4];
      #pragma unroll
      for (int r = 0; r < 4; ++r) {
        const int qrow_l = l4 * 4 + r;
        const int qg = qb0 + w * 16 + qrow_l;
        float sc[4];
        #pragma unroll
        for (int nt = 0; nt < 4; ++nt) sc[nt] = sf[nt][r] * c1 + add_nt[nt];
        if (diag) {
          #pragma unroll
          for (int nt = 0; nt < 4; ++nt)
            if (kg_nt[nt] > qg) sc[nt] = -3.0e38f;
        }
        float mx = fmaxf(fmaxf(sc[0], sc[1]), fmaxf(sc[2], sc[3]));
        #pragma unroll
        for (int d = 1; d < 16; d <<= 1) mx = fmaxf(mx, __shfl_xor(mx, d, 64));
        const float mnew = fmaxf(m_r[r], mx);
        float sum = 0.f;
        #pragma unroll
        for (int nt = 0; nt < 4; ++nt) {
          const float pv = exp2f(sc[nt] - mnew);
          sc[nt] = pv;
          sum += pv;
        }
        #pragma unroll
        for (int d = 1; d < 16; d <<= 1) sum += __shfl_xor(sum, d, 64);
        alpha[r] = exp2f(m_r[r] - mnew);
        l_r[r] = l_r[r] * alpha[r] + sum;
        m_r[r] = mnew;
        #pragma unroll
        for (int nt = 0; nt < 4; ++nt) {
          int pbyte = ((qrow_l * 64 + nt * 16 + l15) * 2) ^ ((qrow_l & 7) << 4);
          *(u16*)((char*)&Ps[w][0] + pbyte) = f32_to_bf16(sc[nt]);
        }
      }

      #pragma unroll
      for (int nt = 0; nt < 8; ++nt)
        #pragma unroll
        for (int r = 0; r < 4; ++r) o[nt][r] *= alpha[r];

      #pragma unroll
      for (int kc = 0; kc < 2; ++kc) {
        int pbyte = ((l15 * 64 + kc * 32 + l4 * 8) * 2) ^ ((l15 & 7) << 4);
        const short8 pf = *(const short8*)((const char*)&Ps[w][0] + pbyte);
        #pragma unroll
        for (int nt = 0; nt < 8; ++nt) {
          const int d = nt * 16 + l15;
          const int vbyte = ((d * 128 + kc * 64 + l4 * 16)) ^ ((d & 7) << 4);
          const short8 vf = *(const short8*)((const char*)Vt + vbyte);
          o[nt] = MFMA16x16x32(pf, vf, o[nt]);
        }
      }
      __syncthreads();
    }

    float rl[4];
    #pragma unroll
    for (int r = 0; r < 4; ++r) rl[r] = 1.0f / l_r[r];
    #pragma unroll
    for (int nt = 0; nt < 8; ++nt) {
      #pragma unroll
      for (int r = 0; r < 4; ++r) {
        const int qg = qb0 + w * 16 + l4 * 4 + r;
        ctx[(long)(b * S + qg) * 2048 + h * 128 + nt * 16 + l15] =
            f32_to_bf16(o[nt][r] * rl[r]);
      }
    }
  }
}

// ---------------- launch ----------------
extern "C" void kernel_launch(void* const* d_in, const int* in_sizes, int n_in,
                              void* d_out, int out_size, void* d_ws, size_t ws_size,
                              hipStream_t stream) {
  const float* x     = (const float*)d_in[0];
  const float* w_qkv = (const float*)d_in[2];
  const float* b_qkv = (const float*)d_in[3];
  const float* w_out = (const float*)d_in[4];
  const float* b_out = (const float*)d_in[5];
  float* out = (float*)d_out;

  // B=2, S=2048, D=2048, H=16, hd=128
  char* ws = (char*)d_ws;
  u16* xb    = (u16*)(ws);                     // 4096x2048   (16.8 MB) dead after GEMM1
  u16* wqkvb = (u16*)(ws + 16777216UL);        // 6144x2048   (25.2 MB) dead after GEMM1
  u16* woutb = (u16*)(ws + 41943040UL);        // 2048x2048   ( 8.4 MB)
  u16* qkvb  = (u16*)(ws + 50331648UL);        // 4096x6144   (50.3 MB)
  u16* ctxb  = (u16*)(ws + 100663296UL);       // 4096x2048   (16.8 MB)
  u16* kimg  = (u16*)(ws);                     // 16.8 MB (overlays xb)
  u16* vimg  = (u16*)(ws + 16777216UL);        // 16.8 MB (overlays wqkvb)

  cvt_f32_bf16<<<2048, 256, 0, stream>>>(x, xb, 8388608 / 4);
  cvt_f32_bf16<<<2048, 256, 0, stream>>>(w_qkv, wqkvb, 12582912 / 4);
  cvt_f32_bf16<<<2048, 256, 0, stream>>>(w_out, woutb, 4194304 / 4);

  gemm_nt_256<1><<<dim3(24, 16), 512, 0, stream>>>(xb, wqkvb, b_qkv, (void*)qkvb, 4096, 6144, 2048);

  repack_kv<<<dim3(32, 16, 2), 256, 0, stream>>>(qkvb, kimg, vimg);

  attn_kernel<<<dim3(16, 16, 2), 256, 0, stream>>>(qkvb, kimg, vimg, ctxb);

  gemm_nt_8p<0><<<dim3(8, 32), 512, 0, stream>>>(ctxb, woutb, b_out, (void*)out, 4096, 2048, 2048);
}

// Round 8
// 307.312 us; speedup vs baseline: 1.0901x; 1.0901x over previous
//
#include <hip/hip_runtime.h>
#include <math.h>

typedef unsigned short u16;
typedef __attribute__((ext_vector_type(8))) short short8;
typedef __attribute__((ext_vector_type(4))) float f32x4;

#define MFMA16x16x32(a, b, c) __builtin_amdgcn_mfma_f32_16x16x32_bf16((a), (b), (c), 0, 0, 0)
#define GLL16(g, s)                                                        \
  __builtin_amdgcn_global_load_lds(                                        \
      (const __attribute__((address_space(1))) void*)(g),                  \
      (__attribute__((address_space(3))) void*)(s), 16, 0, 0)

__device__ __forceinline__ u16 f32_to_bf16(float x) {
  union { float f; unsigned u; } v; v.f = x;
  unsigned r = v.u + 0x7FFFu + ((v.u >> 16) & 1u);
  return (u16)(r >> 16);
}

// ---------------- fp32 -> bf16 convert ----------------
__global__ void cvt_f32_bf16(const float* __restrict__ in, u16* __restrict__ out, int n4) {
  int i = blockIdx.x * blockDim.x + threadIdx.x;
  int stride = gridDim.x * blockDim.x;
  for (; i < n4; i += stride) {
    float4 v = ((const float4*)in)[i];
    ushort4 o;
    o.x = f32_to_bf16(v.x);
    o.y = f32_to_bf16(v.y);
    o.z = f32_to_bf16(v.z);
    o.w = f32_to_bf16(v.w);
    ((ushort4*)out)[i] = o;
  }
}

// ======== 128x256 bf16 NT GEMM, m201-style 2-phase pipeline ========
// 8 waves (2M x 4N), per-wave 64x64. A dbuf 2x16KB, B tribuf 3x32KB = 128KB.
// Per K-tile t:
//  p0: 12 ds_read (af x8, bf01 x4) ; lgkmcnt(0) ; 16 MFMA (n0-1) ; barrier
//  p1: 4 ds_read (bf23) ; stage t+2 (6 GLL) ; vmcnt(6)+lgkmcnt(0) ; 16 MFMA (n2-3) ; barrier
// Gate at p1(t) covers tile t+1 (consumed one phase later) -> reads never wait.
template <int OUT_BF16>
__global__ __launch_bounds__(512, 2) void gemm_nt_p2(
    const u16* __restrict__ A,      // M x K row-major bf16
    const u16* __restrict__ B,      // N x K row-major bf16
    const float* __restrict__ bias, // length N
    void* __restrict__ C,           // M x N (bf16 or f32)
    int M, int N, int K)
{
  __shared__ u16 As[2][8192];    // [buf][128 x 64] swizzled
  __shared__ u16 Bs[3][16384];   // [buf][2 halves x 128 x 64] swizzled

  const int tid = threadIdx.x;
  const int w = tid >> 6, l = tid & 63;
  const int l15 = l & 15, l4 = l >> 4;
  const int wm = w >> 2, wn = w & 3;
  const long bm = (long)blockIdx.y * 128, bn = (long)blockIdx.x * 256;
  const int NT = K >> 6;

  // staging sources (inverse-swizzled): LDS byte q of a 16KB unit holds global
  // (row q>>7, colbyte (q&127)^((row&7)<<4))
  const u16 *aSrc0, *aSrc1, *bSrc0, *bSrc1;
  {
    int q = w * 2048 + l * 16;
    int r = q >> 7, cb = (q & 127) ^ ((r & 7) << 4);
    aSrc0 = A + (bm + r) * (long)K + (cb >> 1);
    bSrc0 = B + (bn + r) * (long)K + (cb >> 1);
    q += 1024;
    r = q >> 7; cb = (q & 127) ^ ((r & 7) << 4);
    aSrc1 = A + (bm + r) * (long)K + (cb >> 1);
    bSrc1 = B + (bn + r) * (long)K + (cb >> 1);
  }
  const long bHS = 128 * (long)K;   // B rows 128..255 (Bh1)
  const int ldst = w * 1024;        // u16 dest within a 16KB unit (wave-uniform)

#define STAGE6(tt)                                                            \
  do {                                                                        \
    const long ko = (long)(tt) * 64;                                          \
    const int vb = (tt) % 3, ab = (tt) & 1;                                   \
    GLL16(aSrc0 + ko, &As[ab][ldst]);                                         \
    GLL16(aSrc1 + ko, &As[ab][ldst + 512]);                                   \
    GLL16(bSrc0 + ko, &Bs[vb][ldst]);                                         \
    GLL16(bSrc1 + ko, &Bs[vb][ldst + 512]);                                   \
    GLL16(bSrc0 + bHS + ko, &Bs[vb][8192 + ldst]);                            \
    GLL16(bSrc1 + bHS + ko, &Bs[vb][8192 + ldst + 512]);                      \
  } while (0)

  const f32x4 z4 = {0.f, 0.f, 0.f, 0.f};
  f32x4 acc[4][4];
  #pragma unroll
  for (int m = 0; m < 4; ++m)
    #pragma unroll
    for (int n = 0; n < 4; ++n) acc[m][n] = z4;

  const int xo0 = (l4 * 16) ^ ((l15 & 7) << 4);
  const int xo1 = (64 + l4 * 16) ^ ((l15 & 7) << 4);

  short8 af[4][2], bf[4][2];

  // prologue: stage tiles 0 and 1; gate tile 0 (leave tile 1's 6 in flight)
  STAGE6(0);
  STAGE6(1);
  asm volatile("s_waitcnt vmcnt(6)\ns_barrier" ::: "memory");

  for (int t = 0; t < NT; ++t) {
    const char* ab = (const char*)&As[t & 1][0] + (wm * 64 + l15) * 128;
    const char* bb = (const char*)&Bs[t % 3][0] + (wn * 32 + l15) * 128;

    // ---- phase 0: reads, clean MFMA cluster (n0-1) ----
    #pragma unroll
    for (int m = 0; m < 4; ++m) {
      af[m][0] = *(const short8*)(ab + m * 2048 + xo0);
      af[m][1] = *(const short8*)(ab + m * 2048 + xo1);
    }
    #pragma unroll
    for (int n = 0; n < 2; ++n) {
      bf[n][0] = *(const short8*)(bb + n * 2048 + xo0);
      bf[n][1] = *(const short8*)(bb + n * 2048 + xo1);
    }
    asm volatile("s_waitcnt lgkmcnt(0)" ::: "memory");
    __builtin_amdgcn_s_setprio(1);
    #pragma unroll
    for (int m = 0; m < 4; ++m)
      #pragma unroll
      for (int n = 0; n < 2; ++n) {
        acc[m][n] = MFMA16x16x32(af[m][0], bf[n][0], acc[m][n]);
        acc[m][n] = MFMA16x16x32(af[m][1], bf[n][1], acc[m][n]);
      }
    __builtin_amdgcn_s_setprio(0);
    asm volatile("s_barrier" ::: "memory");

    // ---- phase 1: reads (bf23), stage t+2, gate t+1, MFMA cluster (n2-3) ----
    #pragma unroll
    for (int n = 0; n < 2; ++n) {
      bf[2 + n][0] = *(const short8*)(bb + 16384 + n * 2048 + xo0);
      bf[2 + n][1] = *(const short8*)(bb + 16384 + n * 2048 + xo1);
    }
    if (t + 2 < NT) STAGE6(t + 2);
    if (t >= NT - 2)
      asm volatile("s_waitcnt vmcnt(0) lgkmcnt(0)" ::: "memory");
    else
      asm volatile("s_waitcnt vmcnt(6) lgkmcnt(0)" ::: "memory");
    __builtin_amdgcn_s_setprio(1);
    #pragma unroll
    for (int m = 0; m < 4; ++m)
      #pragma unroll
      for (int n = 2; n < 4; ++n) {
        acc[m][n] = MFMA16x16x32(af[m][0], bf[n][0], acc[m][n]);
        acc[m][n] = MFMA16x16x32(af[m][1], bf[n][1], acc[m][n]);
      }
    __builtin_amdgcn_s_setprio(0);
    asm volatile("s_barrier" ::: "memory");
  }
#undef STAGE6

  // ---- epilogue ----
  #pragma unroll
  for (int m = 0; m < 4; ++m) {
    const long row0 = bm + wm * 64 + m * 16 + l4 * 4;
    #pragma unroll
    for (int n = 0; n < 4; ++n) {
      const long col = bn + wn * 32 + (n & 1) * 16 + (n >> 1) * 128 + l15;
      const float bv = bias[col];
      #pragma unroll
      for (int r = 0; r < 4; ++r) {
        const float v = acc[m][n][r] + bv;
        if (OUT_BF16)
          ((u16*)C)[(row0 + r) * (long)N + col] = f32_to_bf16(v);
        else
          ((float*)C)[(row0 + r) * (long)N + col] = v;
      }
    }
  }
}

// ---------------- repack K and V into per-tile LDS images ----------------
__global__ __launch_bounds__(256) void repack_kv(
    const u16* __restrict__ qkv, u16* __restrict__ kimg, u16* __restrict__ vimg)
{
  const int t = blockIdx.x;
  const int h = blockIdx.y, b = blockIdx.z;
  const int tid = threadIdx.x;
  __shared__ u16 Vl[64][136];

  const long qbase = ((long)(b * 2048 + t * 64)) * 6144 + h * 128;
  u16* kout = kimg + (((long)(b * 16 + h) * 32 + t) * 8192);
  u16* vout = vimg + (((long)(b * 16 + h) * 32 + t) * 8192);

  #pragma unroll
  for (int i = 0; i < 4; ++i) {
    const int j = tid + i * 256;
    {
      const int r = j >> 4, c8 = (j & 15) * 8;
      uint4 v = *(const uint4*)(qkv + qbase + (long)r * 6144 + 4096 + c8);
      *(uint4*)(&Vl[r][c8]) = v;
    }
    {
      const int byte = j * 16;
      const int r = byte >> 8;
      const int wv = (byte & 255) ^ ((r & 7) << 4);
      const int d0 = wv >> 1;
      uint4 v = *(const uint4*)(qkv + qbase + (long)r * 6144 + 2048 + d0);
      *(uint4*)(kout + j * 8) = v;
    }
  }
  __syncthreads();
  #pragma unroll
  for (int i = 0; i < 4; ++i) {
    const int j = tid + i * 256;
    const int byte = j * 16;
    const int d = byte >> 7;
    const int wv = (byte & 127) ^ ((d & 7) << 4);
    const int k0 = wv >> 1;
    u16 tmp[8];
    #pragma unroll
    for (int m = 0; m < 8; ++m) tmp[m] = Vl[k0 + m][d];
    *(uint4*)(vout + j * 8) = *(const uint4*)tmp;
  }
}

// ---------------- flash causal attention with alibi ----------------
__global__ __launch_bounds__(256) void attn_kernel(
    const u16* __restrict__ qkv,
    const u16* __restrict__ kimg,
    const u16* __restrict__ vimg,
    u16* __restrict__ ctx)
{
  const int S = 2048, NHD = 6144, NT = 32;
  const int p = blockIdx.x, h = blockIdx.y, b = blockIdx.z;
  const int tid = threadIdx.x;
  const int w = tid >> 6, l = tid & 63;
  const int l15 = l & 15, l4 = l >> 4;

  __shared__ u16 Ks[64 * 128];
  __shared__ u16 Vt[128 * 64];
  __shared__ u16 Ps[4][16 * 64];

  const float LOG2E = 1.44269504088896f;
  const float c1 = 0.08838834764831845f * LOG2E;
  const float slope2 = exp2f(-0.5f * (float)(h + 1)) * LOG2E;

  const f32x4 z4 = {0.f, 0.f, 0.f, 0.f};

  for (int pass = 0; pass < 2; ++pass) {
    const int qblk = pass ? (NT - 1 - p) : p;
    const int qb0 = qblk * 64;

    short8 qf[4];
    {
      const int qrow = qb0 + w * 16 + l15;
      const u16* qp = qkv + (long)(b * S + qrow) * NHD + h * 128 + l4 * 8;
      #pragma unroll
      for (int kc = 0; kc < 4; ++kc) qf[kc] = *(const short8*)(qp + kc * 32);
    }

    f32x4 o[8];
    #pragma unroll
    for (int i = 0; i < 8; ++i) o[i] = z4;
    float m_r[4] = {-3.0e38f, -3.0e38f, -3.0e38f, -3.0e38f};
    float l_r[4] = {0.f, 0.f, 0.f, 0.f};

    for (int kt = 0; kt <= qblk; ++kt) {
      const u16* ksrc = kimg + (((long)(b * 16 + h) * NT + kt) * 8192);
      const u16* vsrc = vimg + (((long)(b * 16 + h) * NT + kt) * 8192);
      #pragma unroll
      for (int i = 0; i < 4; ++i) {
        const int chunk = w * 4 + i;
        __builtin_amdgcn_global_load_lds(
            (const __attribute__((address_space(1))) void*)(ksrc + chunk * 512 + l * 8),
            (__attribute__((address_space(3))) void*)(Ks + chunk * 512), 16, 0, 0);
        __builtin_amdgcn_global_load_lds(
            (const __attribute__((address_space(1))) void*)(vsrc + chunk * 512 + l * 8),
            (__attribute__((address_space(3))) void*)(Vt + chunk * 512), 16, 0, 0);
      }
      __syncthreads();

      f32x4 sf[4];
      #pragma unroll
      for (int nt = 0; nt < 4; ++nt) sf[nt] = z4;
      #pragma unroll
      for (int nt = 0; nt < 4; ++nt) {
        const int krow = nt * 16 + l15;
        #pragma unroll
        for (int kc = 0; kc < 4; ++kc) {
          int kbyte = (krow * 256 + kc * 64 + l4 * 16) ^ ((krow & 7) << 4);
          const short8 kf = *(const short8*)((const char*)Ks + kbyte);
          sf[nt] = MFMA16x16x32(qf[kc], kf, sf[nt]);
        }
      }

      float add_nt[4];
      int kg_nt[4];
      #pragma unroll
      for (int nt = 0; nt < 4; ++nt) {
        kg_nt[nt] = kt * 64 + nt * 16 + l15;
        add_nt[nt] = slope2 * (float)(kg_nt[nt] - (S - 1));
      }
      const bool diag = (kt == qblk);
      float alpha[4];
      #pragma unroll
      for (int r = 0; r < 4; ++r) {
        const int qrow_l = l4 * 4 + r;
        const int qg = qb0 + w * 16 + qrow_l;
        float sc[4];
        #pragma unroll
        for (int nt = 0; nt < 4; ++nt) sc[nt] = sf[nt][r] * c1 + add_nt[nt];
        if (diag) {
          #pragma unroll
          for (int nt = 0; nt < 4; ++nt)
            if (kg_nt[nt] > qg) sc[nt] = -3.0e38f;
        }
        float mx = fmaxf(fmaxf(sc[0], sc[1]), fmaxf(sc[2], sc[3]));
        #pragma unroll
        for (int d = 1; d < 16; d <<= 1) mx = fmaxf(mx, __shfl_xor(mx, d, 64));
        const float mnew = fmaxf(m_r[r], mx);
        float sum = 0.f;
        #pragma unroll
        for (int nt = 0; nt < 4; ++nt) {
          const float pv = exp2f(sc[nt] - mnew);
          sc[nt] = pv;
          sum += pv;
        }
        #pragma unroll
        for (int d = 1; d < 16; d <<= 1) sum += __shfl_xor(sum, d, 64);
        alpha[r] = exp2f(m_r[r] - mnew);
        l_r[r] = l_r[r] * alpha[r] + sum;
        m_r[r] = mnew;
        #pragma unroll
        for (int nt = 0; nt < 4; ++nt) {
          int pbyte = ((qrow_l * 64 + nt * 16 + l15) * 2) ^ ((qrow_l & 7) << 4);
          *(u16*)((char*)&Ps[w][0] + pbyte) = f32_to_bf16(sc[nt]);
        }
      }

      #pragma unroll
      for (int nt = 0; nt < 8; ++nt)
        #pragma unroll
        for (int r = 0; r < 4; ++r) o[nt][r] *= alpha[r];

      #pragma unroll
      for (int kc = 0; kc < 2; ++kc) {
        int pbyte = ((l15 * 64 + kc * 32 + l4 * 8) * 2) ^ ((l15 & 7) << 4);
        const short8 pf = *(const short8*)((const char*)&Ps[w][0] + pbyte);
        #pragma unroll
        for (int nt = 0; nt < 8; ++nt) {
          const int d = nt * 16 + l15;
          const int vbyte = ((d * 128 + kc * 64 + l4 * 16)) ^ ((d & 7) << 4);
          const short8 vf = *(const short8*)((const char*)Vt + vbyte);
          o[nt] = MFMA16x16x32(pf, vf, o[nt]);
        }
      }
      __syncthreads();
    }

    float rl[4];
    #pragma unroll
    for (int r = 0; r < 4; ++r) rl[r] = 1.0f / l_r[r];
    #pragma unroll
    for (int nt = 0; nt < 8; ++nt) {
      #pragma unroll
      for (int r = 0; r < 4; ++r) {
        const int qg = qb0 + w * 16 + l4 * 4 + r;
        ctx[(long)(b * S + qg) * 2048 + h * 128 + nt * 16 + l15] =
            f32_to_bf16(o[nt][r] * rl[r]);
      }
    }
  }
}

// ---------------- launch ----------------
extern "C" void kernel_launch(void* const* d_in, const int* in_sizes, int n_in,
                              void* d_out, int out_size, void* d_ws, size_t ws_size,
                              hipStream_t stream) {
  const float* x     = (const float*)d_in[0];
  const float* w_qkv = (const float*)d_in[2];
  const float* b_qkv = (const float*)d_in[3];
  const float* w_out = (const float*)d_in[4];
  const float* b_out = (const float*)d_in[5];
  float* out = (float*)d_out;

  // B=2, S=2048, D=2048, H=16, hd=128
  char* ws = (char*)d_ws;
  u16* xb    = (u16*)(ws);                     // 4096x2048   (16.8 MB) dead after GEMM1
  u16* wqkvb = (u16*)(ws + 16777216UL);        // 6144x2048   (25.2 MB) dead after GEMM1
  u16* woutb = (u16*)(ws + 41943040UL);        // 2048x2048   ( 8.4 MB)
  u16* qkvb  = (u16*)(ws + 50331648UL);        // 4096x6144   (50.3 MB)
  u16* ctxb  = (u16*)(ws + 100663296UL);       // 4096x2048   (16.8 MB)
  u16* kimg  = (u16*)(ws);                     // 16.8 MB (overlays xb)
  u16* vimg  = (u16*)(ws + 16777216UL);        // 16.8 MB (overlays wqkvb)

  cvt_f32_bf16<<<2048, 256, 0, stream>>>(x, xb, 8388608 / 4);
  cvt_f32_bf16<<<2048, 256, 0, stream>>>(w_qkv, wqkvb, 12582912 / 4);
  cvt_f32_bf16<<<2048, 256, 0, stream>>>(w_out, woutb, 4194304 / 4);

  gemm_nt_p2<1><<<dim3(24, 32), 512, 0, stream>>>(xb, wqkvb, b_qkv, (void*)qkvb, 4096, 6144, 2048);

  repack_kv<<<dim3(32, 16, 2), 256, 0, stream>>>(qkvb, kimg, vimg);

  attn_kernel<<<dim3(16, 16, 2), 256, 0, stream>>>(qkvb, kimg, vimg, ctxb);

  gemm_nt_p2<0><<<dim3(8, 32), 512, 0, stream>>>(ctxb, woutb, b_out, (void*)out, 4096, 2048, 2048);
}

// Round 9
// 303.294 us; speedup vs baseline: 1.1045x; 1.0133x over previous
//
#include <hip/hip_runtime.h>
#include <math.h>

typedef unsigned short u16;
typedef __attribute__((ext_vector_type(8))) short short8;
typedef __attribute__((ext_vector_type(4))) float f32x4;

#define MFMA16x16x32(a, b, c) __builtin_amdgcn_mfma_f32_16x16x32_bf16((a), (b), (c), 0, 0, 0)
#define GLL16(g, s)                                                        \
  __builtin_amdgcn_global_load_lds(                                        \
      (const __attribute__((address_space(1))) void*)(g),                  \
      (__attribute__((address_space(3))) void*)(s), 16, 0, 0)

__device__ __forceinline__ u16 f32_to_bf16(float x) {
  union { float f; unsigned u; } v; v.f = x;
  unsigned r = v.u + 0x7FFFu + ((v.u >> 16) & 1u);
  return (u16)(r >> 16);
}

__device__ __forceinline__ void cvt4(const float* in, u16* out, int j) {
  float4 v = ((const float4*)in)[j];
  ushort4 o;
  o.x = f32_to_bf16(v.x);
  o.y = f32_to_bf16(v.y);
  o.z = f32_to_bf16(v.z);
  o.w = f32_to_bf16(v.w);
  ((ushort4*)out)[j] = o;
}

// ---------------- fused fp32 -> bf16 converts (x, w_qkv, w_out) ----------------
__global__ void cvt_all(const float* __restrict__ x, const float* __restrict__ wq,
                        const float* __restrict__ wo, u16* __restrict__ xb,
                        u16* __restrict__ wqb, u16* __restrict__ wob) {
  const int stride = gridDim.x * blockDim.x;
  const int i = blockIdx.x * blockDim.x + threadIdx.x;
  for (int j = i; j < 2097152; j += stride) cvt4(x, xb, j);
  for (int j = i; j < 3145728; j += stride) cvt4(wq, wqb, j);
  for (int j = i; j < 1048576; j += stride) cvt4(wo, wob, j);
}

// ======== 128x128 bf16 NT GEMM, BK=32, tribuf, 3 blocks/CU ========
// 4 waves (2M x 2N), wave-tile 64x64. LDS 48KB: As/Bs [3][128x32].
// LDS layout: 2 M-rows per 128B lds-row; byte for (r, colu16 c):
//   (r>>1)*128 + (((r&1)*64 + 2c) ^ ((r>>1 & 7)<<4))   [verified bijective]
// Pipeline: stage t+2 during t, gate vmcnt(4) (never 0 mid-loop), 1 barrier/tile.
template <int OUT_BF16>
__global__ __launch_bounds__(256, 3) void gemm_k32(
    const u16* __restrict__ A,      // M x K row-major bf16
    const u16* __restrict__ B,      // N x K row-major bf16
    const float* __restrict__ bias, // length N
    void* __restrict__ C,           // M x N (bf16 or f32)
    int M, int N, int K)
{
  __shared__ u16 As[3][4096];   // [buf][128 rows x 32 cols] swizzled (8KB)
  __shared__ u16 Bs[3][4096];

  const int tid = threadIdx.x;
  const int w = tid >> 6, l = tid & 63;
  const int l15 = l & 15, l4 = l >> 4;
  const int wm = w >> 1, wn = w & 1;
  const long bm = (long)blockIdx.y * 128, bn = (long)blockIdx.x * 128;
  const int NT = K >> 5;

  // ---- staging map: 16 chunks of 1KB (A: c 0-7, B: c 0-7) ----
  // wave roles: w0 -> A c0-3, w1 -> A c4-7, w2 -> B c0-3, w3 -> B c4-7
  // chunk c, lane l covers LDS byte o = c*1024 + l*16:
  //   h = (l&7)^(l>>3); src row = 16c + 2*(l>>3) + (h>>2); col u16 = (h&3)*8
  const int h = (l & 7) ^ (l >> 3);
  const int rowoff = 2 * (l >> 3) + (h >> 2);
  const int colofs = (h & 3) * 8;
  const int c0 = (w & 1) * 4;
  const u16* sbase = (w < 2) ? (A + bm * (long)K) : (B + bn * (long)K);
  const u16* src0 = sbase + (long)(16 * (c0 + 0) + rowoff) * K + colofs;
  const u16* src1 = sbase + (long)(16 * (c0 + 1) + rowoff) * K + colofs;
  const u16* src2 = sbase + (long)(16 * (c0 + 2) + rowoff) * K + colofs;
  const u16* src3 = sbase + (long)(16 * (c0 + 3) + rowoff) * K + colofs;

#define STAGE4(tt)                                                            \
  do {                                                                        \
    const int _b = (tt) % 3;                                                  \
    const long _ko = (long)(tt) * 32;                                         \
    u16* _d = (w < 2) ? &As[_b][c0 * 512] : &Bs[_b][c0 * 512];                \
    GLL16(src0 + _ko, _d);                                                    \
    GLL16(src1 + _ko, _d + 512);                                              \
    GLL16(src2 + _ko, _d + 1024);                                             \
    GLL16(src3 + _ko, _d + 1536);                                             \
  } while (0)

  const f32x4 z4 = {0.f, 0.f, 0.f, 0.f};
  f32x4 acc[4][4];
  #pragma unroll
  for (int m = 0; m < 4; ++m)
    #pragma unroll
    for (int n = 0; n < 4; ++n) acc[m][n] = z4;

  // ---- read offsets (per-lane constant) ----
  const int inner = ((l15 & 1) * 64 + l4 * 16) ^ ((l15 >> 1) << 4);
  const int rbase = (l15 >> 1) * 128 + inner;
  const int aOfs = wm * 4096 + rbase;  // + m*1024
  const int bOfs = wn * 4096 + rbase;  // + n*1024

  // prologue: tiles 0,1 in flight; drain tile 0
  STAGE4(0);
  STAGE4(1);
  asm volatile("s_waitcnt vmcnt(4)" ::: "memory");
  __builtin_amdgcn_s_barrier();

  for (int t = 0; t < NT; ++t) {
    const char* aT = (const char*)&As[t % 3][0];
    const char* bT = (const char*)&Bs[t % 3][0];
    short8 af[4], bf[4];
    #pragma unroll
    for (int m = 0; m < 4; ++m) af[m] = *(const short8*)(aT + aOfs + m * 1024);
    #pragma unroll
    for (int n = 0; n < 4; ++n) bf[n] = *(const short8*)(bT + bOfs + n * 1024);
    if (t + 2 < NT) {
      STAGE4(t + 2);
      asm volatile("s_waitcnt vmcnt(4) lgkmcnt(0)" ::: "memory");
    } else {
      asm volatile("s_waitcnt vmcnt(0) lgkmcnt(0)" ::: "memory");
    }
    __builtin_amdgcn_s_setprio(1);
    #pragma unroll
    for (int m = 0; m < 4; ++m)
      #pragma unroll
      for (int n = 0; n < 4; ++n)
        acc[m][n] = MFMA16x16x32(af[m], bf[n], acc[m][n]);
    __builtin_amdgcn_s_setprio(0);
    __builtin_amdgcn_s_barrier();
  }
#undef STAGE4

  // ---- epilogue ----
  #pragma unroll
  for (int m = 0; m < 4; ++m) {
    const long row0 = bm + wm * 64 + m * 16 + l4 * 4;
    #pragma unroll
    for (int n = 0; n < 4; ++n) {
      const long col = bn + wn * 64 + n * 16 + l15;
      const float bv = bias[col];
      #pragma unroll
      for (int r = 0; r < 4; ++r) {
        const float v = acc[m][n][r] + bv;
        if (OUT_BF16)
          ((u16*)C)[(row0 + r) * (long)N + col] = f32_to_bf16(v);
        else
          ((float*)C)[(row0 + r) * (long)N + col] = v;
      }
    }
  }
}

// ---------------- repack K and V into per-tile LDS images ----------------
__global__ __launch_bounds__(256) void repack_kv(
    const u16* __restrict__ qkv, u16* __restrict__ kimg, u16* __restrict__ vimg)
{
  const int t = blockIdx.x;
  const int h = blockIdx.y, b = blockIdx.z;
  const int tid = threadIdx.x;
  __shared__ u16 Vl[64][136];

  const long qbase = ((long)(b * 2048 + t * 64)) * 6144 + h * 128;
  u16* kout = kimg + (((long)(b * 16 + h) * 32 + t) * 8192);
  u16* vout = vimg + (((long)(b * 16 + h) * 32 + t) * 8192);

  #pragma unroll
  for (int i = 0; i < 4; ++i) {
    const int j = tid + i * 256;
    {
      const int r = j >> 4, c8 = (j & 15) * 8;
      uint4 v = *(const uint4*)(qkv + qbase + (long)r * 6144 + 4096 + c8);
      *(uint4*)(&Vl[r][c8]) = v;
    }
    {
      const int byte = j * 16;
      const int r = byte >> 8;
      const int wv = (byte & 255) ^ ((r & 7) << 4);
      const int d0 = wv >> 1;
      uint4 v = *(const uint4*)(qkv + qbase + (long)r * 6144 + 2048 + d0);
      *(uint4*)(kout + j * 8) = v;
    }
  }
  __syncthreads();
  #pragma unroll
  for (int i = 0; i < 4; ++i) {
    const int j = tid + i * 256;
    const int byte = j * 16;
    const int d = byte >> 7;
    const int wv = (byte & 127) ^ ((d & 7) << 4);
    const int k0 = wv >> 1;
    u16 tmp[8];
    #pragma unroll
    for (int m = 0; m < 8; ++m) tmp[m] = Vl[k0 + m][d];
    *(uint4*)(vout + j * 8) = *(const uint4*)tmp;
  }
}

// ---------------- flash causal attention with alibi ----------------
__global__ __launch_bounds__(256) void attn_kernel(
    const u16* __restrict__ qkv,
    const u16* __restrict__ kimg,
    const u16* __restrict__ vimg,
    u16* __restrict__ ctx)
{
  const int S = 2048, NHD = 6144, NT = 32;
  const int p = blockIdx.x, h = blockIdx.y, b = blockIdx.z;
  const int tid = threadIdx.x;
  const int w = tid >> 6, l = tid & 63;
  const int l15 = l & 15, l4 = l >> 4;

  __shared__ u16 Ks[64 * 128];
  __shared__ u16 Vt[128 * 64];
  __shared__ u16 Ps[4][16 * 64];

  const float LOG2E = 1.44269504088896f;
  const float c1 = 0.08838834764831845f * LOG2E;
  const float slope2 = exp2f(-0.5f * (float)(h + 1)) * LOG2E;

  const f32x4 z4 = {0.f, 0.f, 0.f, 0.f};

  for (int pass = 0; pass < 2; ++pass) {
    const int qblk = pass ? (NT - 1 - p) : p;
    const int qb0 = qblk * 64;

    short8 qf[4];
    {
      const int qrow = qb0 + w * 16 + l15;
      const u16* qp = qkv + (long)(b * S + qrow) * NHD + h * 128 + l4 * 8;
      #pragma unroll
      for (int kc = 0; kc < 4; ++kc) qf[kc] = *(const short8*)(qp + kc * 32);
    }

    f32x4 o[8];
    #pragma unroll
    for (int i = 0; i < 8; ++i) o[i] = z4;
    float m_r[4] = {-3.0e38f, -3.0e38f, -3.0e38f, -3.0e38f};
    float l_r[4] = {0.f, 0.f, 0.f, 0.f};

    for (int kt = 0; kt <= qblk; ++kt) {
      const u16* ksrc = kimg + (((long)(b * 16 + h) * NT + kt) * 8192);
      const u16* vsrc = vimg + (((long)(b * 16 + h) * NT + kt) * 8192);
      #pragma unroll
      for (int i = 0; i < 4; ++i) {
        const int chunk = w * 4 + i;
        __builtin_amdgcn_global_load_lds(
            (const __attribute__((address_space(1))) void*)(ksrc + chunk * 512 + l * 8),
            (__attribute__((address_space(3))) void*)(Ks + chunk * 512), 16, 0, 0);
        __builtin_amdgcn_global_load_lds(
            (const __attribute__((address_space(1))) void*)(vsrc + chunk * 512 + l * 8),
            (__attribute__((address_space(3))) void*)(Vt + chunk * 512), 16, 0, 0);
      }
      __syncthreads();

      // ---- QK^T ----
      f32x4 sf[4];
      #pragma unroll
      for (int nt = 0; nt < 4; ++nt) sf[nt] = z4;
      #pragma unroll
      for (int nt = 0; nt < 4; ++nt) {
        const int krow = nt * 16 + l15;
        #pragma unroll
        for (int kc = 0; kc < 4; ++kc) {
          int kbyte = (krow * 256 + kc * 64 + l4 * 16) ^ ((krow & 7) << 4);
          const short8 kf = *(const short8*)((const char*)Ks + kbyte);
          sf[nt] = MFMA16x16x32(qf[kc], kf, sf[nt]);
        }
      }

      // ---- online softmax: interleaved shuffle reductions (4-way ILP) ----
      float add_nt[4];
      int kg_nt[4];
      #pragma unroll
      for (int nt = 0; nt < 4; ++nt) {
        kg_nt[nt] = kt * 64 + nt * 16 + l15;
        add_nt[nt] = slope2 * (float)(kg_nt[nt] - (S - 1));
      }
      const bool diag = (kt == qblk);
      float sc[4][4], mxv[4];
      #pragma unroll
      for (int r = 0; r < 4; ++r) {
        const int qg = qb0 + w * 16 + l4 * 4 + r;
        #pragma unroll
        for (int nt = 0; nt < 4; ++nt) {
          float s = sf[nt][r] * c1 + add_nt[nt];
          if (diag && kg_nt[nt] > qg) s = -3.0e38f;
          sc[r][nt] = s;
        }
        mxv[r] = fmaxf(fmaxf(sc[r][0], sc[r][1]), fmaxf(sc[r][2], sc[r][3]));
      }
      #pragma unroll
      for (int d = 1; d < 16; d <<= 1) {
        #pragma unroll
        for (int r = 0; r < 4; ++r)
          mxv[r] = fmaxf(mxv[r], __shfl_xor(mxv[r], d, 64));
      }
      float alpha[4], sum[4];
      #pragma unroll
      for (int r = 0; r < 4; ++r) {
        const float mnew = fmaxf(m_r[r], mxv[r]);
        sum[r] = 0.f;
        #pragma unroll
        for (int nt = 0; nt < 4; ++nt) {
          const float pv = exp2f(sc[r][nt] - mnew);
          sc[r][nt] = pv;
          sum[r] += pv;
        }
        alpha[r] = exp2f(m_r[r] - mnew);
        m_r[r] = mnew;
      }
      #pragma unroll
      for (int d = 1; d < 16; d <<= 1) {
        #pragma unroll
        for (int r = 0; r < 4; ++r) sum[r] += __shfl_xor(sum[r], d, 64);
      }
      #pragma unroll
      for (int r = 0; r < 4; ++r) l_r[r] = l_r[r] * alpha[r] + sum[r];

      // ---- write P (bf16) to per-wave LDS, swizzled ----
      #pragma unroll
      for (int r = 0; r < 4; ++r) {
        const int qrow_l = l4 * 4 + r;
        #pragma unroll
        for (int nt = 0; nt < 4; ++nt) {
          int pbyte = ((qrow_l * 64 + nt * 16 + l15) * 2) ^ ((qrow_l & 7) << 4);
          *(u16*)((char*)&Ps[w][0] + pbyte) = f32_to_bf16(sc[r][nt]);
        }
      }

      // ---- rescale O, then PV ----
      #pragma unroll
      for (int nt = 0; nt < 8; ++nt)
        #pragma unroll
        for (int r = 0; r < 4; ++r) o[nt][r] *= alpha[r];

      #pragma unroll
      for (int kc = 0; kc < 2; ++kc) {
        int pbyte = ((l15 * 64 + kc * 32 + l4 * 8) * 2) ^ ((l15 & 7) << 4);
        const short8 pf = *(const short8*)((const char*)&Ps[w][0] + pbyte);
        #pragma unroll
        for (int nt = 0; nt < 8; ++nt) {
          const int d = nt * 16 + l15;
          const int vbyte = ((d * 128 + kc * 64 + l4 * 16)) ^ ((d & 7) << 4);
          const short8 vf = *(const short8*)((const char*)Vt + vbyte);
          o[nt] = MFMA16x16x32(pf, vf, o[nt]);
        }
      }
      __syncthreads();
    }

    float rl[4];
    #pragma unroll
    for (int r = 0; r < 4; ++r) rl[r] = 1.0f / l_r[r];
    #pragma unroll
    for (int nt = 0; nt < 8; ++nt) {
      #pragma unroll
      for (int r = 0; r < 4; ++r) {
        const int qg = qb0 + w * 16 + l4 * 4 + r;
        ctx[(long)(b * S + qg) * 2048 + h * 128 + nt * 16 + l15] =
            f32_to_bf16(o[nt][r] * rl[r]);
      }
    }
  }
}

// ---------------- launch ----------------
extern "C" void kernel_launch(void* const* d_in, const int* in_sizes, int n_in,
                              void* d_out, int out_size, void* d_ws, size_t ws_size,
                              hipStream_t stream) {
  const float* x     = (const float*)d_in[0];
  const float* w_qkv = (const float*)d_in[2];
  const float* b_qkv = (const float*)d_in[3];
  const float* w_out = (const float*)d_in[4];
  const float* b_out = (const float*)d_in[5];
  float* out = (float*)d_out;

  // B=2, S=2048, D=2048, H=16, hd=128
  char* ws = (char*)d_ws;
  u16* xb    = (u16*)(ws);                     // 4096x2048   (16.8 MB) dead after GEMM1
  u16* wqkvb = (u16*)(ws + 16777216UL);        // 6144x2048   (25.2 MB) dead after GEMM1
  u16* woutb = (u16*)(ws + 41943040UL);        // 2048x2048   ( 8.4 MB)
  u16* qkvb  = (u16*)(ws + 50331648UL);        // 4096x6144   (50.3 MB)
  u16* ctxb  = (u16*)(ws + 100663296UL);       // 4096x2048   (16.8 MB)
  u16* kimg  = (u16*)(ws);                     // 16.8 MB (overlays xb)
  u16* vimg  = (u16*)(ws + 16777216UL);        // 16.8 MB (overlays wqkvb)

  cvt_all<<<2048, 256, 0, stream>>>(x, w_qkv, w_out, xb, wqkvb, woutb);

  gemm_k32<1><<<dim3(48, 32), 256, 0, stream>>>(xb, wqkvb, b_qkv, (void*)qkvb, 4096, 6144, 2048);

  repack_kv<<<dim3(32, 16, 2), 256, 0, stream>>>(qkvb, kimg, vimg);

  attn_kernel<<<dim3(16, 16, 2), 256, 0, stream>>>(qkvb, kimg, vimg, ctxb);

  gemm_k32<0><<<dim3(16, 32), 256, 0, stream>>>(ctxb, woutb, b_out, (void*)out, 4096, 2048, 2048);
}